// Round 1
// baseline (23.909 us; speedup 1.0000x reference)
//
#include <hip/hip_runtime.h>

// Blur+downsample: (32,512,512,3) f32 NHWC, 2x2 depthwise kernel, stride 2, SAME.
// SAME pad is 0 here (512 even, k=2, s=2) -> non-overlapping weighted 2x2 pool.
// out[b,oh,ow,c] = k00*x[2oh,2ow] + k01*x[2oh,2ow+1] + k10*x[2oh+1,2ow] + k11*x[2oh+1,2ow+1]

#define BATCH 32
#define H 512
#define W 512
#define C 3
#define OH (H / 2)
#define OW (W / 2)
#define ROWF (W * C)    // 1536 floats per input row
#define OROWF (OW * C)  // 768 floats per output row

__global__ __launch_bounds__(256) void blur_ds_kernel(
    const float* __restrict__ x, const float* __restrict__ kern,
    float* __restrict__ out) {
  // One block per (b, oh). The two input rows it needs are contiguous:
  // rows 2*oh and 2*oh+1 of image b -> one 3072-float (12 KB) span.
  __shared__ float lds[2 * ROWF];  // 12 KB

  const int blk = blockIdx.x;  // b*OH + oh
  const int t = threadIdx.x;

  const float k00 = kern[0];
  const float k01 = kern[1];
  const float k10 = kern[2];
  const float k11 = kern[3];

  const int b = blk >> 8;    // / OH (OH == 256)
  const int oh = blk & 255;  // % OH

  const float* src = x + (size_t)(b * H + 2 * oh) * ROWF;  // 16B-aligned

  // Stage 3072 floats = 768 float4 with fully coalesced loads (3 per thread).
  const float4* s4 = (const float4*)src;
  float4* l4 = (float4*)lds;
#pragma unroll
  for (int i = 0; i < 3; ++i) {
    l4[t + i * 256] = s4[t + i * 256];
  }
  __syncthreads();

  float* orow = out + (size_t)blk * OROWF;

  // 768 output floats per row, 3 per thread; output flat index f -> (ow, c):
  // ow = f/3, c = f%3; input element within row g = 6*ow + c.
  // LDS read stride across lanes ~2 words -> 2-way bank aliasing (free).
#pragma unroll
  for (int i = 0; i < 3; ++i) {
    const int f = t + i * 256;
    const int ow = f / 3;
    const int c = f - 3 * ow;
    const int g = 6 * ow + c;
    const float v = k00 * lds[g] + k01 * lds[g + 3] + k10 * lds[ROWF + g] +
                    k11 * lds[ROWF + g + 3];
    orow[f] = v;  // stride-1 across lanes -> fully coalesced stores
  }
}

extern "C" void kernel_launch(void* const* d_in, const int* in_sizes, int n_in,
                              void* d_out, int out_size, void* d_ws,
                              size_t ws_size, hipStream_t stream) {
  const float* x = (const float*)d_in[0];
  const float* kern = (const float*)d_in[1];
  float* out = (float*)d_out;

  const int nblocks = BATCH * OH;  // 8192
  blur_ds_kernel<<<nblocks, 256, 0, stream>>>(x, kern, out);
}